// Round 6
// baseline (607.423 us; speedup 1.0000x reference)
//
#include <hip/hip_runtime.h>

// out[t, n*16+f] = relu(bias[f] + sum_{l=0}^{31} x[t-1-2l, n] * w_pn[l, f])
// w_pn = relu(w) / ||relu(w)||_2 (per filter column, over 32 lags)
//
// T=2048, N=4096, L=32, F=16, dilation=2.
//
// R6: PER-BLOCK SEQUENTIAL WRITE STREAMS + amortized reads.
// Evidence: R3 (t-pair x all-N, per-block sequential 8KB-granule streams)
// hit 4.0 TB/s COMBINED (553MB reads + 537MB writes / 271us) -- fastest
// memory rate of any round; its loss was the 553MB redundant x reads.
// R5 (compacted scattered front, 32MiB) = null: open-row capacity is only
// ~4MiB device-wide, so any independent-block scatter stays activate-bound
// (~2.6 TB/s, tFAW). Per-block sequential streams keep ~1 open row per
// stream (2048 streams < ~4096 banks) regardless of global front.
// This version: block = 8 same-parity t's x all N (256 blocks, 1/CU):
// same 2048 streams as R3, but x-reads drop 553 -> 164 MB (each staged
// row feeds 8 outputs, not 2). Double-buffered chunk staging, one
// barrier per chunk; stores fire-and-forget, pace = write drain.

constexpr int T = 2048;
constexpr int N = 4096;
constexpr int L = 32;
constexpr int F = 16;
constexpr int KT = 8;              // same-parity t's per block (t span = 16)
constexpr int NC = 128;            // n columns per chunk
constexpr int NCHUNK = N / NC;     // 32
constexpr int NR = 39;             // staged rows: g = t0-63+2r, r = 0..38
constexpr int OUT_STRIDE = N * F;  // 65536

typedef float f4 __attribute__((ext_vector_type(4)));
typedef float f2 __attribute__((ext_vector_type(2)));

__global__ __launch_bounds__(256, 1)
void tlayer_kernel(const float* __restrict__ x,
                   const float* __restrict__ w,
                   const float* __restrict__ bias,
                   float* __restrict__ out)
{
    __shared__ __align__(16) float xs[2][NR * NC];   // 2 x 19.5 KiB
    __shared__ float sw[L * F];                      // 2 KiB
    __shared__ float sscale[F];

    const int tid = threadIdx.x;
    const int g   = blockIdx.x;            // 0..255
    // 8 same-parity t's: t = t0 + 2i, i = 0..7; covers [16b, 16b+16) per parity
    const int t0  = (g & 1) + (g >> 1) * 16;

    // ---- weight prep (redundant per block; trivial) ----
    sw[tid]       = fmaxf(w[tid], 0.f);
    sw[tid + 256] = fmaxf(w[tid + 256], 0.f);
    __syncthreads();
    if (tid < F) {
        float s = 0.f;
        #pragma unroll
        for (int l = 0; l < L; ++l) { float v = sw[l * F + tid]; s += v * v; }
        sscale[tid] = rsqrtf(fmaxf(s, 1e-12f));
    }
    __syncthreads();
    sw[tid]       *= sscale[tid & 15];
    sw[tid + 256] *= sscale[tid & 15];

    // ---- staging map: slot idx in [0, NR*32): r = idx>>5, c4 = idx&31 ----
    // global row g(r) = t0 - 63 + 2r (same parity as t0-1); max = t0+13 <= 2046.

    // prologue: stage chunk 0 into xs[0] (runs concurrent with sw scale-apply;
    // disjoint LDS; the barrier below covers both)
    {
        #pragma unroll
        for (int u = 0; u < 4; ++u) {
            const int idx = tid + u * 256;           // < 1024 < 1248, all valid
            const int r = idx >> 5, c4 = idx & 31;
            const int gr = t0 - 63 + 2 * r;
            f4 v = {0.f, 0.f, 0.f, 0.f};
            if (gr >= 0) v = *(const f4*)(x + (size_t)gr * N + c4 * 4);
            *(f4*)(&xs[0][r * NC + c4 * 4]) = v;
        }
        if (tid < 224) {                              // idx = 1024..1247
            const int idx = tid + 1024;
            const int r = idx >> 5, c4 = idx & 31;
            const int gr = t0 - 63 + 2 * r;
            f4 v = {0.f, 0.f, 0.f, 0.f};
            if (gr >= 0) v = *(const f4*)(x + (size_t)gr * N + c4 * 4);
            *(f4*)(&xs[0][r * NC + c4 * 4]) = v;
        }
    }
    __syncthreads();

    const int fp  = tid & 7;           // filter pair: f = 2*fp, 2*fp+1
    const int nl4 = tid >> 3;          // 0..31, owns n-quad nl4*4..+3 of chunk

    f2 wr[L];                          // 64 VGPRs
    #pragma unroll
    for (int l = 0; l < L; ++l)
        wr[l] = *(const f2*)(sw + l * F + fp * 2);
    const f2 b2 = *(const f2*)(bias + fp * 2);

    #pragma unroll 1
    for (int c = 0; c < NCHUNK; ++c) {
        const int cur = c & 1;

        // issue next chunk's global loads early (consumed after compute+store)
        f4 ld[5];
        if (c + 1 < NCHUNK) {
            const int cn1 = (c + 1) * NC;
            #pragma unroll
            for (int u = 0; u < 4; ++u) {
                const int idx = tid + u * 256;
                const int r = idx >> 5, c4 = idx & 31;
                const int gr = t0 - 63 + 2 * r;
                ld[u] = {0.f, 0.f, 0.f, 0.f};
                if (gr >= 0) ld[u] = *(const f4*)(x + (size_t)gr * N + cn1 + c4 * 4);
            }
            ld[4] = {0.f, 0.f, 0.f, 0.f};
            if (tid < 224) {
                const int idx = tid + 1024;
                const int r = idx >> 5, c4 = idx & 31;
                const int gr = t0 - 63 + 2 * r;
                if (gr >= 0) ld[4] = *(const f4*)(x + (size_t)gr * N + cn1 + c4 * 4);
            }
        }

        // compute: row r serves t_i = t0+2i at lag 31+i-r (valid i <= r <= 31+i)
        f2 acc[KT][4];
        #pragma unroll
        for (int i = 0; i < KT; ++i)
            #pragma unroll
            for (int k = 0; k < 4; ++k) acc[i][k] = b2;

        #pragma unroll
        for (int r = 0; r < NR; ++r) {
            const f4 xv = *(const f4*)(&xs[cur][r * NC + nl4 * 4]);
            #pragma unroll
            for (int i = 0; i < KT; ++i) {
                if (r >= i && r <= 31 + i) {
                    const f2 wl = wr[31 + i - r];
                    acc[i][0] += wl * xv[0];
                    acc[i][1] += wl * xv[1];
                    acc[i][2] += wl * xv[2];
                    acc[i][3] += wl * xv[3];
                }
            }
        }

        // stores: 8 streams (one per t), each advancing sequentially with c
        const int cb = c * NC + nl4 * 4;
        #pragma unroll
        for (int i = 0; i < KT; ++i) {
            float* orow = out + (size_t)(t0 + 2 * i) * OUT_STRIDE + fp * 2;
            #pragma unroll
            for (int k = 0; k < 4; ++k) {
                f2 v;
                v[0] = fmaxf(acc[i][k][0], 0.f);
                v[1] = fmaxf(acc[i][k][1], 0.f);
                *(f2*)(orow + (size_t)(cb + k) * F) = v;
            }
        }

        // land prefetched chunk into the other buffer
        if (c + 1 < NCHUNK) {
            #pragma unroll
            for (int u = 0; u < 4; ++u) {
                const int idx = tid + u * 256;
                const int r = idx >> 5, c4 = idx & 31;
                *(f4*)(&xs[cur ^ 1][r * NC + c4 * 4]) = ld[u];
            }
            if (tid < 224) {
                const int idx = tid + 1024;
                const int r = idx >> 5, c4 = idx & 31;
                *(f4*)(&xs[cur ^ 1][r * NC + c4 * 4]) = ld[4];
            }
        }
        __syncthreads();
    }
}

extern "C" void kernel_launch(void* const* d_in, const int* in_sizes, int n_in,
                              void* d_out, int out_size, void* d_ws, size_t ws_size,
                              hipStream_t stream) {
    const float* x    = (const float*)d_in[0];   // [2048, 4096]
    const float* w    = (const float*)d_in[1];   // [32, 16]
    const float* bias = (const float*)d_in[2];   // [16]
    float* out = (float*)d_out;                  // [2048, 65536]

    dim3 grid(256);                              // 1 block/CU, 8 t-streams each
    tlayer_kernel<<<grid, 256, 0, stream>>>(x, w, bias, out);
}